// Round 11
// baseline (39.068 us; speedup 1.0000x reference)
//
#include <hip/hip_runtime.h>

#define RES   256
#define NANG  180
#define NRAYS 256
#define NPIX  (RES * RES)
#define OUTP  (NANG * NRAYS)

#define PITCH 258                    // padded row pitch (uint4 elems)
#define PADN  (PITCH * PITCH)        // 66564 padded pixels

// shallow blocks first (fat: 16 samples/thread), then steep (8 samples/thread)
#define SHALLOW_BLOCKS (90 * 8)      // 90 angles x 8 groups of 32 rays, all 256 steps
#define STEEP_BLOCKS   (90 * 16)     // 90 angles x 16 ray-quads(16): wave = 2 rays x 32 steps
#define TOTAL_BLOCKS   (SHALLOW_BLOCKS + STEEP_BLOCKS)

typedef _Float16 half2v __attribute__((ext_vector_type(2)));

__device__ __forceinline__ float hdot(unsigned int p, half2v w, float acc) {
#if __has_builtin(__builtin_amdgcn_fdot2)
    return __builtin_amdgcn_fdot2(__builtin_bit_cast(half2v, p), w, acc, false);
#else
    half2v v = __builtin_bit_cast(half2v, p);
    return acc + (float)v.x * (float)w.x + (float)v.y * (float)w.y;
#endif
}

// pre-pass: imgs[4][256][256] -> two padded pair images.
// X-layout (for shallow angles):  timgX[y*PITCH+x] = {half2(v_b(y-1,x-1), v_b(y-1,x))}
// T-layout (for steep angles):    timgT[x*PITCH+y] = {half2(v_b(y-1,x-1), v_b(y,x-1))}
//   (pairs along y, linearized column-major: consecutive steps of a near-vertical
//    ray are CONTIGUOUS uint4s -> ~8x fewer L1 lines per wave-gather at 90 deg)
__global__ __launch_bounds__(256) void pad_pairs(
    const float* __restrict__ imgs,
    uint4* __restrict__ timgX, uint4* __restrict__ timgT)
{
    const int idx = blockIdx.x * 256 + threadIdx.x;
    if (idx >= PADN) return;
    const int p = idx / PITCH, q = idx - p * PITCH;

    // ---- X-layout entry (y=p, x=q): pair over x at row y-1
    {
        const int iy = p - 1;
        const bool ry = (unsigned)iy < (unsigned)RES;
        const bool c0 = ry && ((unsigned)(q - 1) < (unsigned)RES);
        const bool c1 = ry && ((unsigned)q < (unsigned)RES);
        const int s0 = iy * RES + (q - 1);
        const int s1 = iy * RES + q;
        unsigned int u[4];
#pragma unroll
        for (int b = 0; b < 4; ++b) {
            const float v0 = c0 ? imgs[b * NPIX + s0] : 0.0f;
            const float v1 = c1 ? imgs[b * NPIX + s1] : 0.0f;
            half2v h; h.x = (_Float16)v0; h.y = (_Float16)v1;
            u[b] = __builtin_bit_cast(unsigned int, h);
        }
        timgX[idx] = make_uint4(u[0], u[1], u[2], u[3]);
    }

    // ---- T-layout entry (x=p, y=q): pair over y at col x-1
    {
        const int ix = p - 1;
        const bool rx = (unsigned)ix < (unsigned)RES;
        const bool c0 = rx && ((unsigned)(q - 1) < (unsigned)RES);
        const bool c1 = rx && ((unsigned)q < (unsigned)RES);
        const int s0 = (q - 1) * RES + ix;
        const int s1 = q * RES + ix;
        unsigned int u[4];
#pragma unroll
        for (int b = 0; b < 4; ++b) {
            const float v0 = c0 ? imgs[b * NPIX + s0] : 0.0f;
            const float v1 = c1 ? imgs[b * NPIX + s1] : 0.0f;
            half2v h; h.x = (_Float16)v0; h.y = (_Float16)v1;
            u[b] = __builtin_bit_cast(unsigned int, h);
        }
        timgT[idx] = make_uint4(u[0], u[1], u[2], u[3]);
    }
}

struct Geom { float srx, sry, ddx, ddy, scale; };

__device__ __forceinline__ Geom make_geom(const float* __restrict__ angles,
                                          const float* __restrict__ rays,
                                          int a, int r)
{
    float sn, cs;
    sincosf(angles[a], &sn, &cs);
    const float4 ray = reinterpret_cast<const float4*>(rays)[r];
    const float dxr = ray.z - ray.x, dyr = ray.w - ray.y;
    const float len = sqrtf(dxr * dxr + dyr * dyr);
    Geom g;
    g.srx = cs * ray.x - sn * ray.y + 127.5f;
    g.sry = sn * ray.x + cs * ray.y + 127.5f;
    g.ddx = (cs * ray.z - sn * ray.w + 127.5f) - g.srx;
    g.ddy = (sn * ray.z + cs * ray.w + 127.5f) - g.sry;
    g.scale = len * (1.0f / RES);
    return g;
}

// 8 bilinear samples, batched: phase A issues all 16 uint4 gathers into
// registers, phase B does the fdot2 math. Coordinate roles are symmetric:
// pass (fx,fy) with timgX, or (fy,fx) with timgT — identical code.
// A = pair-dimension coordinate, B = row-dimension coordinate.
// NOTE: fA/fB are BY VALUE — the caller's coords are NOT advanced.
__device__ __forceinline__ void sample8(
    const uint4* __restrict__ timg,
    float fA, float fB, float dA, float dB,
    float acc0[4], float acc1[4])
{
    uint4 r0[8], r1[8];
    float wAv[8], wBv[8];

#pragma unroll
    for (int j = 0; j < 8; ++j) {
        const float A0 = floorf(fA), B0 = floorf(fB);
        wAv[j] = fA - A0;
        wBv[j] = fB - B0;
        const int idx = (int)B0 * PITCH + (int)A0 + (PITCH + 1);
        r0[j] = timg[idx];
        r1[j] = timg[idx + PITCH];
        fA += dA; fB += dB;
    }

#pragma unroll
    for (int j = 0; j < 8; ++j) {
        const float wA = wAv[j], wB = wBv[j];
        const float w11 = wA * wB;
        const float w01 = wA - w11;      // pair-elem1, row0
        const float w10 = wB - w11;      // pair-elem0, row1
        const float w00 = (1.0f - wA) - w10;

        half2v wa; wa.x = (_Float16)w00; wa.y = (_Float16)w01;
        half2v wb; wb.x = (_Float16)w10; wb.y = (_Float16)w11;

        float* acc = (j & 1) ? acc1 : acc0;
        acc[0] = hdot(r0[j].x, wa, hdot(r1[j].x, wb, acc[0]));
        acc[1] = hdot(r0[j].y, wa, hdot(r1[j].y, wb, acc[1]));
        acc[2] = hdot(r0[j].z, wa, hdot(r1[j].z, wb, acc[2]));
        acc[3] = hdot(r0[j].w, wa, hdot(r1[j].w, wb, acc[3]));
    }
}

__global__ __launch_bounds__(512, 4) void radon_main(
    const uint4*  __restrict__ timgX,
    const uint4*  __restrict__ timgT,
    const float*  __restrict__ angles,
    const float*  __restrict__ rays,
    float*        __restrict__ out)
{
    const int bid = blockIdx.x;
    const int tid = threadIdx.x;

    if (bid < SHALLOW_BLOCKS) {
        // lanes = rays (x-contiguous at shallow angles); X-layout image.
        const int as = bid >> 3;                  // 0..89
        const int rg = bid & 7;                   // group of 32 rays
        const int a  = (as < 45) ? as : as + 90;
        const int tx = tid & 31;                  // ray lane
        const int ty = tid >> 5;                  // step chunk 0..15
        const int r  = rg * 32 + tx;

        const Geom g = make_geom(angles, rays, a, r);
        float acc0[4] = {0.f, 0.f, 0.f, 0.f};
        float acc1[4] = {0.f, 0.f, 0.f, 0.f};

        const float dfx = g.ddx * (1.0f / RES);
        const float dfy = g.ddy * (1.0f / RES);
        float fx = fmaf(((float)(ty * 8) + 0.5f) * (1.0f / RES), g.ddx, g.srx);
        float fy = fmaf(((float)(ty * 8) + 0.5f) * (1.0f / RES), g.ddy, g.sry);

        // first half: steps ty*8 .. ty*8+7
        sample8(timgX, fx, fy, dfx, dfy, acc0, acc1);
        // second half: steps ty*8+128 .. ty*8+135 (sample8 is by-value, so
        // advance the FULL 128 steps here)
        fx += g.ddx * (128.0f / RES);
        fy += g.ddy * (128.0f / RES);
        sample8(timgX, fx, fy, dfx, dfy, acc0, acc1);

        __shared__ float red[4][16][32];
#pragma unroll
        for (int b = 0; b < 4; ++b) red[b][ty][tx] = acc0[b] + acc1[b];
        __syncthreads();

        if (tid < 128) {
            const int b  = tid >> 5;
            const int t2 = tid & 31;
            float s = 0.f;
#pragma unroll
            for (int j = 0; j < 16; ++j) s += red[b][j][t2];
            out[b * OUTP + a * NRAYS + rg * 32 + t2] = s * g.scale;
        }
    } else {
        // lanes = steps along ray; T-layout image (steps contiguous in memory
        // at steep angles). wave = 2 rays x 32 steps.
        const int b2   = bid - SHALLOW_BLOCKS;
        const int a    = (b2 >> 4) + 45;          // 45..134
        const int rq   = b2 & 15;
        const int w    = tid >> 6;
        const int lane = tid & 63;
        const int half = lane >> 5;
        const int sub  = lane & 31;
        const int r    = rq * 16 + w * 2 + half;

        const Geom g = make_geom(angles, rays, a, r);
        float acc0[4] = {0.f, 0.f, 0.f, 0.f};
        float acc1[4] = {0.f, 0.f, 0.f, 0.f};

        float fx = fmaf(((float)sub + 0.5f) * (1.0f / RES), g.ddx, g.srx);
        float fy = fmaf(((float)sub + 0.5f) * (1.0f / RES), g.ddy, g.sry);
        const float dfx = g.ddx * 0.125f;
        const float dfy = g.ddy * 0.125f;

        // swapped args: pair-dim = y, row-dim = x
        sample8(timgT, fy, fx, dfy, dfx, acc0, acc1);

        float a0 = acc0[0] + acc1[0];
        float a1 = acc0[1] + acc1[1];
        float a2 = acc0[2] + acc1[2];
        float a3 = acc0[3] + acc1[3];

#pragma unroll
        for (int m = 1; m < 32; m <<= 1) {
            a0 += __shfl_xor(a0, m, 64);
            a1 += __shfl_xor(a1, m, 64);
            a2 += __shfl_xor(a2, m, 64);
            a3 += __shfl_xor(a3, m, 64);
        }
        if (sub == 0) {
            const int base = a * NRAYS + r;
            out[0 * OUTP + base] = a0 * g.scale;
            out[1 * OUTP + base] = a1 * g.scale;
            out[2 * OUTP + base] = a2 * g.scale;
            out[3 * OUTP + base] = a3 * g.scale;
        }
    }
}

// ---- fallback (no workspace): simple clamped per-ray kernel, known-correct, f32
__global__ __launch_bounds__(256) void radon_simple(
    const float* __restrict__ imgs,
    const float* __restrict__ angles,
    const float* __restrict__ rays,
    float* __restrict__ out)
{
    const int a = blockIdx.x;
    const int r = threadIdx.x;
    const Geom g = make_geom(angles, rays, a, r);
    float a0 = 0.f, a1 = 0.f, a2 = 0.f, a3 = 0.f;
    for (int k = 0; k < RES; ++k) {
        const float t  = ((float)k + 0.5f) * (1.0f / RES);
        const float fx = fmaf(t, g.ddx, g.srx);
        const float fy = fmaf(t, g.ddy, g.sry);
        const float x0f = floorf(fx), y0f = floorf(fy);
        const float wx = fx - x0f, wy = fy - y0f;
        const int x0 = (int)x0f, y0 = (int)y0f;
        const bool vx0 = (unsigned)x0 < (unsigned)RES;
        const bool vx1 = (unsigned)(x0 + 1) < (unsigned)RES;
        const bool vy0 = (unsigned)y0 < (unsigned)RES;
        const bool vy1 = (unsigned)(y0 + 1) < (unsigned)RES;
        const int x0c = min(max(x0, 0), RES - 1), x1c = min(max(x0 + 1, 0), RES - 1);
        const int y0c = min(max(y0, 0), RES - 1), y1c = min(max(y0 + 1, 0), RES - 1);
        const float omwx = 1.0f - wx, omwy = 1.0f - wy;
        const float w00 = (vx0 && vy0) ? omwx * omwy : 0.f;
        const float w01 = (vx1 && vy0) ? wx * omwy : 0.f;
        const float w10 = (vx0 && vy1) ? omwx * wy : 0.f;
        const float w11 = (vx1 && vy1) ? wx * wy : 0.f;
        const int i00 = y0c * RES + x0c, i01 = y0c * RES + x1c;
        const int i10 = y1c * RES + x0c, i11 = y1c * RES + x1c;
        a0 = fmaf(w00, imgs[i00], fmaf(w01, imgs[i01], fmaf(w10, imgs[i10], fmaf(w11, imgs[i11], a0))));
        a1 = fmaf(w00, imgs[NPIX + i00], fmaf(w01, imgs[NPIX + i01], fmaf(w10, imgs[NPIX + i10], fmaf(w11, imgs[NPIX + i11], a1))));
        a2 = fmaf(w00, imgs[2 * NPIX + i00], fmaf(w01, imgs[2 * NPIX + i01], fmaf(w10, imgs[2 * NPIX + i10], fmaf(w11, imgs[2 * NPIX + i11], a2))));
        a3 = fmaf(w00, imgs[3 * NPIX + i00], fmaf(w01, imgs[3 * NPIX + i01], fmaf(w10, imgs[3 * NPIX + i10], fmaf(w11, imgs[3 * NPIX + i11], a3))));
    }
    const int base = a * NRAYS + r;
    out[0 * OUTP + base] = a0 * g.scale;
    out[1 * OUTP + base] = a1 * g.scale;
    out[2 * OUTP + base] = a2 * g.scale;
    out[3 * OUTP + base] = a3 * g.scale;
}

extern "C" void kernel_launch(void* const* d_in, const int* in_sizes, int n_in,
                              void* d_out, int out_size, void* d_ws, size_t ws_size,
                              hipStream_t stream) {
    const float* imgs   = (const float*)d_in[0];
    const float* angles = (const float*)d_in[1];
    const float* rays   = (const float*)d_in[2];
    float* out = (float*)d_out;

    const size_t one = (size_t)PADN * sizeof(uint4);

    if (ws_size >= 2 * one) {
        uint4* timgX = (uint4*)d_ws;
        uint4* timgT = (uint4*)((char*)d_ws + one);
        pad_pairs<<<(PADN + 255) / 256, 256, 0, stream>>>(imgs, timgX, timgT);
        radon_main<<<TOTAL_BLOCKS, 512, 0, stream>>>(timgX, timgT, angles, rays, out);
    } else {
        radon_simple<<<NANG, NRAYS, 0, stream>>>(imgs, angles, rays, out);
    }
}

// Round 12
// 34.578 us; speedup vs baseline: 1.1299x; 1.1299x over previous
//
#include <hip/hip_runtime.h>

#define RES   256
#define NANG  180
#define NRAYS 256
#define NPIX  (RES * RES)
#define OUTP  (NANG * NRAYS)

#define PITCH 258                    // padded row pitch (uint4 elems)
#define PADN  (PITCH * PITCH)        // 66564 padded pixels

// shallow blocks first (fat: 16 samples/thread), then steep (8 samples/thread)
#define SHALLOW_BLOCKS (90 * 8)      // 90 angles x 8 groups of 32 rays, all 256 steps
#define STEEP_BLOCKS   (90 * 16)     // 90 angles x 16 ray-quads(16): wave = 2 rays x 32 steps
#define TOTAL_BLOCKS   (SHALLOW_BLOCKS + STEEP_BLOCKS)

typedef _Float16 half2v __attribute__((ext_vector_type(2)));

__device__ __forceinline__ float hdot(unsigned int p, half2v w, float acc) {
#if __has_builtin(__builtin_amdgcn_fdot2)
    return __builtin_amdgcn_fdot2(__builtin_bit_cast(half2v, p), w, acc, false);
#else
    half2v v = __builtin_bit_cast(half2v, p);
    return acc + (float)v.x * (float)w.x + (float)v.y * (float)w.y;
#endif
}

// pre-pass: imgs[4][256][256] -> padded pair image.
// ppx[y][x] = { half2(v_b(y-1,x-1), v_b(y-1,x)) for b=0..3 }  (0 outside image)
__global__ __launch_bounds__(256) void pad_pairs(
    const float* __restrict__ imgs, uint4* __restrict__ timg)
{
    const int idx = blockIdx.x * 256 + threadIdx.x;
    if (idx >= PADN) return;
    const int y = idx / PITCH, x = idx - y * PITCH;
    const int iy = y - 1;
    const bool ry = (unsigned)iy < (unsigned)RES;
    const bool r0 = ry && ((unsigned)(x - 1) < (unsigned)RES);
    const bool r1 = ry && ((unsigned)x < (unsigned)RES);
    const int s0 = iy * RES + (x - 1);
    const int s1 = iy * RES + x;

    unsigned int u[4];
#pragma unroll
    for (int b = 0; b < 4; ++b) {
        const float v0 = r0 ? imgs[b * NPIX + s0] : 0.0f;
        const float v1 = r1 ? imgs[b * NPIX + s1] : 0.0f;
        half2v h; h.x = (_Float16)v0; h.y = (_Float16)v1;
        u[b] = __builtin_bit_cast(unsigned int, h);
    }
    timg[idx] = make_uint4(u[0], u[1], u[2], u[3]);
}

struct Geom { float srx, sry, ddx, ddy, scale; };

__device__ __forceinline__ Geom make_geom(const float* __restrict__ angles,
                                          const float* __restrict__ rays,
                                          int a, int r)
{
    float sn, cs;
    sincosf(angles[a], &sn, &cs);
    const float4 ray = reinterpret_cast<const float4*>(rays)[r];
    const float dxr = ray.z - ray.x, dyr = ray.w - ray.y;
    const float len = sqrtf(dxr * dxr + dyr * dyr);
    Geom g;
    g.srx = cs * ray.x - sn * ray.y + 127.5f;
    g.sry = sn * ray.x + cs * ray.y + 127.5f;
    g.ddx = (cs * ray.z - sn * ray.w + 127.5f) - g.srx;
    g.ddy = (sn * ray.z + cs * ray.w + 127.5f) - g.sry;
    g.scale = len * (1.0f / RES);
    return g;
}

// 8 bilinear samples, batched: phase A issues all 16 uint4 gathers into
// registers (load ILP), phase B does the fdot2 math. acc split 2-way to
// shorten the fdot2 dependency chain.
__device__ __forceinline__ void sample8(
    const uint4* __restrict__ timg,
    float& fx, float& fy, float dfx, float dfy,
    float acc0[4], float acc1[4])
{
    uint4 r0[8], r1[8];
    float wxv[8], wyv[8];

#pragma unroll
    for (int j = 0; j < 8; ++j) {
        const float x0f = floorf(fx), y0f = floorf(fy);
        wxv[j] = fx - x0f;
        wyv[j] = fy - y0f;
        const int idx = (int)y0f * PITCH + (int)x0f + (PITCH + 1);
        r0[j] = timg[idx];
        r1[j] = timg[idx + PITCH];
        fx += dfx; fy += dfy;
    }

#pragma unroll
    for (int j = 0; j < 8; ++j) {
        const float wx = wxv[j], wy = wyv[j];
        const float w11 = wx * wy;
        const float w01 = wx - w11;
        const float w10 = wy - w11;
        const float w00 = (1.0f - wx) - w10;

        half2v wa; wa.x = (_Float16)w00; wa.y = (_Float16)w01;
        half2v wb; wb.x = (_Float16)w10; wb.y = (_Float16)w11;

        float* acc = (j & 1) ? acc1 : acc0;
        acc[0] = hdot(r0[j].x, wa, hdot(r1[j].x, wb, acc[0]));
        acc[1] = hdot(r0[j].y, wa, hdot(r1[j].y, wb, acc[1]));
        acc[2] = hdot(r0[j].z, wa, hdot(r1[j].z, wb, acc[2]));
        acc[3] = hdot(r0[j].w, wa, hdot(r1[j].w, wb, acc[3]));
    }
}

__global__ __launch_bounds__(512, 4) void radon_main(
    const uint4*  __restrict__ timg,
    const float*  __restrict__ angles,
    const float*  __restrict__ rays,
    float*        __restrict__ out)
{
    const int bid = blockIdx.x;
    const int tid = threadIdx.x;

    if (bid < SHALLOW_BLOCKS) {
        // lanes = rays (x-contiguous at shallow angles).
        // block = 32 rays x 256 steps; thread (tx,ty): 16 samples at
        // k = sg*128 + ty*8 + j  (sg=0..1, j=0..7); LDS reduce over ty.
        const int as = bid >> 3;                  // 0..89
        const int rg = bid & 7;                   // group of 32 rays
        const int a  = (as < 45) ? as : as + 90;
        const int tx = tid & 31;                  // ray lane
        const int ty = tid >> 5;                  // step chunk 0..15
        const int r  = rg * 32 + tx;

        const Geom g = make_geom(angles, rays, a, r);
        float acc0[4] = {0.f, 0.f, 0.f, 0.f};
        float acc1[4] = {0.f, 0.f, 0.f, 0.f};

        const float dfx = g.ddx * (1.0f / RES);
        const float dfy = g.ddy * (1.0f / RES);
        float fx = fmaf(((float)(ty * 8) + 0.5f) * (1.0f / RES), g.ddx, g.srx);
        float fy = fmaf(((float)(ty * 8) + 0.5f) * (1.0f / RES), g.ddy, g.sry);

        // first half: steps ty*8 .. ty*8+7 (sample8 advances fx,fy by 8 steps)
        sample8(timg, fx, fy, dfx, dfy, acc0, acc1);
        // jump the remaining 120 steps to the second 128-step half
        fx += g.ddx * (120.0f / RES);
        fy += g.ddy * (120.0f / RES);
        sample8(timg, fx, fy, dfx, dfy, acc0, acc1);

        // transposed LDS reduce: red[b][ty][tx], conflict-free on read
        __shared__ float red[4][16][32];
#pragma unroll
        for (int b = 0; b < 4; ++b) red[b][ty][tx] = acc0[b] + acc1[b];
        __syncthreads();

        if (tid < 128) {
            const int b  = tid >> 5;
            const int t2 = tid & 31;
            float s = 0.f;
#pragma unroll
            for (int j = 0; j < 16; ++j) s += red[b][j][t2];
            out[b * OUTP + a * NRAYS + rg * 32 + t2] = s * g.scale;
        }
    } else {
        // lanes = steps along ray (x-contiguous at steep angles); wave = 2 rays x 32 steps
        const int b2   = bid - SHALLOW_BLOCKS;
        const int a    = (b2 >> 4) + 45;          // 45..134
        const int rq   = b2 & 15;
        const int w    = tid >> 6;
        const int lane = tid & 63;
        const int half = lane >> 5;
        const int sub  = lane & 31;
        const int r    = rq * 16 + w * 2 + half;

        const Geom g = make_geom(angles, rays, a, r);
        float acc0[4] = {0.f, 0.f, 0.f, 0.f};
        float acc1[4] = {0.f, 0.f, 0.f, 0.f};

        float fx = fmaf(((float)sub + 0.5f) * (1.0f / RES), g.ddx, g.srx);
        float fy = fmaf(((float)sub + 0.5f) * (1.0f / RES), g.ddy, g.sry);
        const float dfx = g.ddx * 0.125f;
        const float dfy = g.ddy * 0.125f;

        sample8(timg, fx, fy, dfx, dfy, acc0, acc1);

        float a0 = acc0[0] + acc1[0];
        float a1 = acc0[1] + acc1[1];
        float a2 = acc0[2] + acc1[2];
        float a3 = acc0[3] + acc1[3];

#pragma unroll
        for (int m = 1; m < 32; m <<= 1) {
            a0 += __shfl_xor(a0, m, 64);
            a1 += __shfl_xor(a1, m, 64);
            a2 += __shfl_xor(a2, m, 64);
            a3 += __shfl_xor(a3, m, 64);
        }
        if (sub == 0) {
            const int base = a * NRAYS + r;
            out[0 * OUTP + base] = a0 * g.scale;
            out[1 * OUTP + base] = a1 * g.scale;
            out[2 * OUTP + base] = a2 * g.scale;
            out[3 * OUTP + base] = a3 * g.scale;
        }
    }
}

// ---- fallback (no workspace): simple clamped per-ray kernel, known-correct, f32
__global__ __launch_bounds__(256) void radon_simple(
    const float* __restrict__ imgs,
    const float* __restrict__ angles,
    const float* __restrict__ rays,
    float* __restrict__ out)
{
    const int a = blockIdx.x;
    const int r = threadIdx.x;
    const Geom g = make_geom(angles, rays, a, r);
    float a0 = 0.f, a1 = 0.f, a2 = 0.f, a3 = 0.f;
    for (int k = 0; k < RES; ++k) {
        const float t  = ((float)k + 0.5f) * (1.0f / RES);
        const float fx = fmaf(t, g.ddx, g.srx);
        const float fy = fmaf(t, g.ddy, g.sry);
        const float x0f = floorf(fx), y0f = floorf(fy);
        const float wx = fx - x0f, wy = fy - y0f;
        const int x0 = (int)x0f, y0 = (int)y0f;
        const bool vx0 = (unsigned)x0 < (unsigned)RES;
        const bool vx1 = (unsigned)(x0 + 1) < (unsigned)RES;
        const bool vy0 = (unsigned)y0 < (unsigned)RES;
        const bool vy1 = (unsigned)(y0 + 1) < (unsigned)RES;
        const int x0c = min(max(x0, 0), RES - 1), x1c = min(max(x0 + 1, 0), RES - 1);
        const int y0c = min(max(y0, 0), RES - 1), y1c = min(max(y0 + 1, 0), RES - 1);
        const float omwx = 1.0f - wx, omwy = 1.0f - wy;
        const float w00 = (vx0 && vy0) ? omwx * omwy : 0.f;
        const float w01 = (vx1 && vy0) ? wx * omwy : 0.f;
        const float w10 = (vx0 && vy1) ? omwx * wy : 0.f;
        const float w11 = (vx1 && vy1) ? wx * wy : 0.f;
        const int i00 = y0c * RES + x0c, i01 = y0c * RES + x1c;
        const int i10 = y1c * RES + x0c, i11 = y1c * RES + x1c;
        a0 = fmaf(w00, imgs[i00], fmaf(w01, imgs[i01], fmaf(w10, imgs[i10], fmaf(w11, imgs[i11], a0))));
        a1 = fmaf(w00, imgs[NPIX + i00], fmaf(w01, imgs[NPIX + i01], fmaf(w10, imgs[NPIX + i10], fmaf(w11, imgs[NPIX + i11], a1))));
        a2 = fmaf(w00, imgs[2 * NPIX + i00], fmaf(w01, imgs[2 * NPIX + i01], fmaf(w10, imgs[2 * NPIX + i10], fmaf(w11, imgs[2 * NPIX + i11], a2))));
        a3 = fmaf(w00, imgs[3 * NPIX + i00], fmaf(w01, imgs[3 * NPIX + i01], fmaf(w10, imgs[3 * NPIX + i10], fmaf(w11, imgs[3 * NPIX + i11], a3))));
    }
    const int base = a * NRAYS + r;
    out[0 * OUTP + base] = a0 * g.scale;
    out[1 * OUTP + base] = a1 * g.scale;
    out[2 * OUTP + base] = a2 * g.scale;
    out[3 * OUTP + base] = a3 * g.scale;
}

extern "C" void kernel_launch(void* const* d_in, const int* in_sizes, int n_in,
                              void* d_out, int out_size, void* d_ws, size_t ws_size,
                              hipStream_t stream) {
    const float* imgs   = (const float*)d_in[0];
    const float* angles = (const float*)d_in[1];
    const float* rays   = (const float*)d_in[2];
    float* out = (float*)d_out;

    const size_t need = (size_t)PADN * sizeof(uint4);

    if (ws_size >= need) {
        uint4* timg = (uint4*)d_ws;
        pad_pairs<<<(PADN + 255) / 256, 256, 0, stream>>>(imgs, timg);
        radon_main<<<TOTAL_BLOCKS, 512, 0, stream>>>(timg, angles, rays, out);
    } else {
        radon_simple<<<NANG, NRAYS, 0, stream>>>(imgs, angles, rays, out);
    }
}